// Round 6
// baseline (22.923 us; speedup 1.0000x reference)
//
#include <hip/hip_runtime.h>

#define S_LEN 512
#define H_DIM 768
#define BS_TOK 8192      // B*S
#define NCOLS 80         // 64 mlp + 2 proj + 14 zero-pad
#define KSPLIT 4
#define KSEG 192         // K per wcat segment
#define KPAD 200         // B row stride in bf16 elems (400B)
#define WSEG (NCOLS * KPAD)   // 16000 elems = 32000B per seg image
#define TOKB 25          // tokens per block
#define ROWS 32          // TOKB + 7 halo, 2 tiles of 16
#define GRID ((BS_TOK + TOKB - 1) / TOKB)   // 328

typedef __attribute__((ext_vector_type(8))) short short8v;
typedef __attribute__((ext_vector_type(4))) short short4v;
typedef __attribute__((ext_vector_type(4))) float f32x4;

__device__ __forceinline__ short f2bf(float f) {
  union { float f; unsigned u; } x; x.f = f;
  unsigned r = x.u + 0x7fffu + ((x.u >> 16) & 1u);
  return (short)(r >> 16);
}

// ===== kprep: build wcat[KSPLIT][NCOLS][KPAD] bf16 — exact LDS images =====
__global__ __launch_bounds__(256) void kprep(const float* __restrict__ tw,
                                             const float* __restrict__ w1,
                                             const float* __restrict__ wsc,
                                             short* __restrict__ wcat) {
  int i = blockIdx.x * 256 + threadIdx.x;
  if (i >= KSPLIT * WSEG) return;
  int kseg = i / WSEG;
  int rem  = i - kseg * WSEG;
  int c    = rem / KPAD;
  int koff = rem - c * KPAD;
  float v = 0.f;
  if (koff < KSEG && c < 66) {
    int k = kseg * KSEG + koff;
    if (c < 64) v = tw[k] * w1[(size_t)k * 64 + c];
    else        v = wsc[(size_t)k * 2 + (c - 64)];
  }
  wcat[i] = f2bf(v);
}

// ===== kFused: GEMM (K-split across waves) + MLP epilogue + prefix softmax =====
// waves 0,1: K 0..383 (segs 0,1), row tiles 0,1.  waves 2,3: K 384..767 (segs 2,3).
__global__ __launch_bounds__(256, 2) void kFused(const float* __restrict__ hidden,
                                                 const short* __restrict__ wcat,
                                                 const float* __restrict__ b1,
                                                 const float* __restrict__ w2,
                                                 const float* __restrict__ b2,
                                                 const float* __restrict__ bsc,
                                                 float* __restrict__ out) {
  __shared__ short bsA[WSEG];        // 32000 B : current seg for K-half 0
  __shared__ short bsB[WSEG];        // 32000 B : current seg for K-half 1
  __shared__ float red[ROWS][NCOLS]; // 10240 B : K-half-1 partial acc
  __shared__ float lp[40][4];        // logit, p0, p1 per row slot

  const int tid  = threadIdx.x;
  const int t0   = blockIdx.x * TOKB;
  const int w    = tid >> 6;
  const int lane = tid & 63;
  const int ci   = lane & 15;
  const int g    = lane >> 4;
  const int kg   = g * 8;
  const int h    = w >> 1;           // K-half
  const int tile = w & 1;            // row tile
  const int rrow = min(t0 + tile * 16 + ci, BS_TOK - 1);

  // ---- 1) B round-1 loads to regs: segs {0,2} (oldest in queue) ----
  short8v breg[16];
#pragma unroll
  for (int it = 0; it < 16; ++it) {
    int i = tid + 256 * it;
    if (i < 4000) {
      int sel = (i >= 2000);
      int e   = i - sel * 2000;
      breg[it] = *reinterpret_cast<const short8v*>(
          wcat + (size_t)(sel * 2) * WSEG + (size_t)e * 8);
    }
  }

  // ---- 2) ALL A loads for this wave's K-half (24 x float4, stay in flight) ----
  const float* aptr = hidden + (size_t)rrow * H_DIM + h * 384 + kg;
  float4 abuf[24];
#pragma unroll
  for (int q = 0; q < 12; ++q) {
    abuf[2 * q]     = *reinterpret_cast<const float4*>(aptr + q * 32);
    abuf[2 * q + 1] = *reinterpret_cast<const float4*>(aptr + q * 32 + 4);
  }

  // ---- 3) write B round-1 to LDS ----
#pragma unroll
  for (int it = 0; it < 16; ++it) {
    int i = tid + 256 * it;
    if (i < 4000) {
      int sel = (i >= 2000);
      int e   = i - sel * 2000;
      *reinterpret_cast<short8v*>((sel ? bsB : bsA) + e * 8) = breg[it];
    }
  }
  __syncthreads();   // (1)

  f32x4 acc[5];
#pragma unroll
  for (int nt = 0; nt < 5; ++nt) acc[nt] = (f32x4){0.f, 0.f, 0.f, 0.f};
  const short* myb = h ? bsB : bsA;

  // ---- 4) MFMA round 1 (seg h*2, abuf[0..11]) ----
#pragma unroll
  for (int ks = 0; ks < 6; ++ks) {
    const float4 a0 = abuf[2 * ks];
    const float4 a1 = abuf[2 * ks + 1];
    short8v av;
    av[0] = f2bf(a0.x); av[1] = f2bf(a0.y); av[2] = f2bf(a0.z); av[3] = f2bf(a0.w);
    av[4] = f2bf(a1.x); av[5] = f2bf(a1.y); av[6] = f2bf(a1.z); av[7] = f2bf(a1.w);
#pragma unroll
    for (int nt = 0; nt < 5; ++nt) {
      short8v bb = *reinterpret_cast<const short8v*>(&myb[(nt * 16 + ci) * KPAD + ks * 32 + kg]);
      acc[nt] = __builtin_amdgcn_mfma_f32_16x16x32_bf16(av, bb, acc[nt], 0, 0, 0);
    }
  }

  // ---- 5) B round-2 loads to regs: segs {1,3} (L2-hot) ----
#pragma unroll
  for (int it = 0; it < 16; ++it) {
    int i = tid + 256 * it;
    if (i < 4000) {
      int sel = (i >= 2000);
      int e   = i - sel * 2000;
      breg[it] = *reinterpret_cast<const short8v*>(
          wcat + (size_t)(sel * 2 + 1) * WSEG + (size_t)e * 8);
    }
  }
  __syncthreads();   // (2) everyone done reading round-1 LDS

#pragma unroll
  for (int it = 0; it < 16; ++it) {
    int i = tid + 256 * it;
    if (i < 4000) {
      int sel = (i >= 2000);
      int e   = i - sel * 2000;
      *reinterpret_cast<short8v*>((sel ? bsB : bsA) + e * 8) = breg[it];
    }
  }
  __syncthreads();   // (3)

  // ---- 6) MFMA round 2 (seg h*2+1, abuf[12..23]) ----
#pragma unroll
  for (int ks = 0; ks < 6; ++ks) {
    const float4 a0 = abuf[12 + 2 * ks];
    const float4 a1 = abuf[12 + 2 * ks + 1];
    short8v av;
    av[0] = f2bf(a0.x); av[1] = f2bf(a0.y); av[2] = f2bf(a0.z); av[3] = f2bf(a0.w);
    av[4] = f2bf(a1.x); av[5] = f2bf(a1.y); av[6] = f2bf(a1.z); av[7] = f2bf(a1.w);
#pragma unroll
    for (int nt = 0; nt < 5; ++nt) {
      short8v bb = *reinterpret_cast<const short8v*>(&myb[(nt * 16 + ci) * KPAD + ks * 32 + kg]);
      acc[nt] = __builtin_amdgcn_mfma_f32_16x16x32_bf16(av, bb, acc[nt], 0, 0, 0);
    }
  }

  // ---- 7) reduce K-halves via LDS ----
  if (h == 1) {
#pragma unroll
    for (int j = 0; j < 4; ++j) {
      int r = tile * 16 + 4 * g + j;
#pragma unroll
      for (int nt = 0; nt < 5; ++nt)
        red[r][nt * 16 + ci] = acc[nt][j];
    }
  }
  __syncthreads();   // (4)

  if (h == 0) {
    const float4 bb1 = *reinterpret_cast<const float4*>(b1 + 4 * ci);
    const float4 ww2 = *reinterpret_cast<const float4*>(w2 + 4 * ci);
    const float b2v  = b2[0];
#pragma unroll
    for (int j = 0; j < 4; ++j) {
      int r = tile * 16 + 4 * g + j;
      // finish the 4 mlp cols this lane owns in nt 0..3, plus p in nt 4
      float z0 = acc[0][j] + red[r][ci]        + bb1.x;
      float z1 = acc[1][j] + red[r][16 + ci]   + bb1.y;
      float z2 = acc[2][j] + red[r][32 + ci]   + bb1.z;
      float z3 = acc[3][j] + red[r][48 + ci]   + bb1.w;
      // NOTE: bb1/ww2 are b1[4*ci..4*ci+3], but cols owned are ci,16+ci,32+ci,48+ci.
      // Use per-col scalars instead:
      (void)z0; (void)z1; (void)z2; (void)z3;
      float s = 0.f;
#pragma unroll
      for (int nt = 0; nt < 4; ++nt) {
        int c = nt * 16 + ci;
        float z = acc[nt][j] + red[r][c] + b1[c];
        z = fmaxf(z, 0.f);
        s += z * w2[c];
      }
#pragma unroll
      for (int msk = 1; msk < 16; msk <<= 1) s += __shfl_xor(s, msk, 64);
      float pv = acc[4][j] + red[r][64 + ci];
      if (ci == 0) lp[r][0] = s + b2v;
      if (ci < 2)  lp[r][1 + ci] = pv;
    }
  }
  __syncthreads();   // (5)

  // ---- 8) prefix softmax + output ----
  if (tid < TOKB) {
    int t = t0 + tid;
    if (t < BS_TOK) {
      int s_ = t & (S_LEN - 1);
      int nmax = min(8, S_LEN - s_);
      float bs0 = bsc[0], bs1 = bsc[1];
      float m = lp[tid][0];
      float d = 1.f;
      float n0 = lp[tid][1], n1 = lp[tid][2];
      float o[16];
      o[0] = n0 + bs0; o[1] = n1 + bs1;
#pragma unroll
      for (int j = 1; j < 8; ++j) {
        if (j < nmax) {
          float L  = lp[tid + j][0];
          float nm = fmaxf(m, L);
          float sc = __expf(m - nm);
          float e  = __expf(L - nm);
          d  = d  * sc + e;
          n0 = n0 * sc + e * lp[tid + j][1];
          n1 = n1 * sc + e * lp[tid + j][2];
          m = nm;
        }
        float inv = 1.f / d;
        o[2 * j]     = n0 * inv + bs0;
        o[2 * j + 1] = n1 * inv + bs1;
      }
      float4* op = reinterpret_cast<float4*>(out + (size_t)t * 16);
#pragma unroll
      for (int i = 0; i < 4; ++i) op[i] = *reinterpret_cast<float4*>(&o[4 * i]);
    }
  }
}

// ===== fallback path (tiny ws) =====

__global__ __launch_bounds__(256) void kprepS(const float* __restrict__ tw,
                                              const float* __restrict__ w1,
                                              const float* __restrict__ wsc,
                                              short* __restrict__ wcat) {
  int i = blockIdx.x * 256 + threadIdx.x;
  if (i >= NCOLS * H_DIM) return;
  int c = i / H_DIM, k = i - c * H_DIM;
  float v = 0.f;
  if (c < 64)       v = tw[k] * w1[k * 64 + c];
  else if (c == 64) v = wsc[k * 2 + 0];
  else if (c == 65) v = wsc[k * 2 + 1];
  wcat[i] = f2bf(v);
}

__global__ __launch_bounds__(256) void k1s(const float* __restrict__ hidden,
                                           const short* __restrict__ wcat,
                                           const float* __restrict__ b1,
                                           const float* __restrict__ w2,
                                           const float* __restrict__ b2,
                                           float* __restrict__ logit,
                                           float* __restrict__ pbuf) {
  __shared__ short as[64 * 72];
  __shared__ short bss[NCOLS * 72];
  const int tid  = threadIdx.x;
  const int t0   = blockIdx.x * 64;
  const int w    = tid >> 6;
  const int lane = tid & 63;
  const int ci   = lane & 15;
  const int kg   = (lane >> 4) * 8;
  const int arow = w * 16 + ci;

  f32x4 acc[5];
#pragma unroll
  for (int nt = 0; nt < 5; ++nt) acc[nt] = (f32x4){0.f, 0.f, 0.f, 0.f};

  for (int cc = 0; cc < H_DIM / 64; ++cc) {
    const int k0 = cc * 64;
    __syncthreads();
#pragma unroll
    for (int i = 0; i < 4; ++i) {
      int f = tid + 256 * i;
      int r = f >> 4, c4 = f & 15;
      const float4 v = *reinterpret_cast<const float4*>(
          hidden + (size_t)(t0 + r) * H_DIM + k0 + c4 * 4);
      short4v bv;
      bv[0] = f2bf(v.x); bv[1] = f2bf(v.y); bv[2] = f2bf(v.z); bv[3] = f2bf(v.w);
      *reinterpret_cast<short4v*>(&as[r * 72 + c4 * 4]) = bv;
    }
    for (int i = tid; i < NCOLS * 8; i += 256) {
      int r = i >> 3, c8 = i & 7;
      short8v v = *reinterpret_cast<const short8v*>(wcat + r * H_DIM + k0 + c8 * 8);
      *reinterpret_cast<short8v*>(&bss[r * 72 + c8 * 8]) = v;
    }
    __syncthreads();
#pragma unroll
    for (int ks = 0; ks < 64; ks += 32) {
      short8v a = *reinterpret_cast<const short8v*>(&as[arow * 72 + ks + kg]);
#pragma unroll
      for (int nt = 0; nt < 5; ++nt) {
        short8v bb = *reinterpret_cast<const short8v*>(&bss[(nt * 16 + ci) * 72 + ks + kg]);
        acc[nt] = __builtin_amdgcn_mfma_f32_16x16x32_bf16(a, bb, acc[nt], 0, 0, 0);
      }
    }
  }

  const int g = lane >> 4;
  float lg[4];
#pragma unroll
  for (int j = 0; j < 4; ++j) {
    float sacc = 0.f;
#pragma unroll
    for (int nt = 0; nt < 4; ++nt) {
      int c = nt * 16 + ci;
      float z = acc[nt][j] + b1[c];
      z = fmaxf(z, 0.f);
      sacc += z * w2[c];
    }
#pragma unroll
    for (int msk = 1; msk < 16; msk <<= 1) sacc += __shfl_xor(sacc, msk, 64);
    lg[j] = sacc;
  }
  const float b2v = b2[0];
#pragma unroll
  for (int j = 0; j < 4; ++j) {
    int rg = t0 + w * 16 + 4 * g + j;
    if (ci == 0) {
      logit[rg] = lg[j] + b2v;
      pbuf[rg * 2 + 0] = acc[4][j];
    } else if (ci == 1) {
      pbuf[rg * 2 + 1] = acc[4][j];
    }
  }
}

__global__ __launch_bounds__(256) void k3g(const float* __restrict__ logit,
                                           const float* __restrict__ pbuf,
                                           const float* __restrict__ bsc,
                                           float* __restrict__ out) {
  int t = blockIdx.x * 256 + threadIdx.x;
  int s = t & (S_LEN - 1);
  int nmax = min(8, S_LEN - s);
  float bs0 = bsc[0], bs1 = bsc[1];
  float m = logit[t];
  float d = 1.f;
  float n0 = pbuf[2 * t], n1 = pbuf[2 * t + 1];
  float o[16];
  o[0] = n0 + bs0; o[1] = n1 + bs1;
#pragma unroll
  for (int j = 1; j < 8; ++j) {
    if (j < nmax) {
      float L  = logit[t + j];
      float nm = fmaxf(m, L);
      float sc = __expf(m - nm);
      float e  = __expf(L - nm);
      d  = d  * sc + e;
      n0 = n0 * sc + e * pbuf[2 * (t + j)];
      n1 = n1 * sc + e * pbuf[2 * (t + j) + 1];
      m = nm;
    }
    float inv = 1.f / d;
    o[2 * j]     = n0 * inv + bs0;
    o[2 * j + 1] = n1 * inv + bs1;
  }
  float4* op = reinterpret_cast<float4*>(out + (size_t)t * 16);
#pragma unroll
  for (int i = 0; i < 4; ++i) op[i] = *reinterpret_cast<float4*>(&o[4 * i]);
}

// ===== launch =====

extern "C" void kernel_launch(void* const* d_in, const int* in_sizes, int n_in,
                              void* d_out, int out_size, void* d_ws, size_t ws_size,
                              hipStream_t stream) {
  const float* hidden = (const float*)d_in[0];
  const float* tw     = (const float*)d_in[1];
  const float* w1     = (const float*)d_in[2];
  const float* b1     = (const float*)d_in[3];
  const float* w2     = (const float*)d_in[4];
  const float* b2     = (const float*)d_in[5];
  const float* wsc    = (const float*)d_in[6];
  const float* bsc    = (const float*)d_in[7];
  float* out = (float*)d_out;
  char* ws = (char*)d_ws;

  const size_t wcat_bytes = (size_t)KSPLIT * WSEG * 2;   // 128,000

  if (ws_size >= wcat_bytes) {
    short* wcat = (short*)ws;
    kprep <<<(KSPLIT * WSEG + 255) / 256, 256, 0, stream>>>(tw, w1, wsc, wcat);
    kFused<<<GRID, 256, 0, stream>>>(hidden, wcat, b1, w2, b2, bsc, out);
  } else {
    short* wcat  = (short*)ws;
    float* logit = (float*)(ws + 131072);
    float* pbuf  = (float*)(ws + 131072 + 32768);
    kprepS<<<(NCOLS * H_DIM + 255) / 256, 256, 0, stream>>>(tw, w1, wsc, wcat);
    k1s<<<BS_TOK / 64, 256, 0, stream>>>(hidden, wcat, b1, w2, b2, logit, pbuf);
    k3g<<<BS_TOK / 256, 256, 0, stream>>>(logit, pbuf, bsc, out);
  }
}